// Round 6
// baseline (24.959 us; speedup 1.0000x reference)
//
#include <hip/hip_runtime.h>
#include <hip/hip_bf16.h>

#define ALPHA 1.0f
#define INV_BETA 0.5f

#define B_ 16
#define H_ 256
#define W_ 256
#define SEG 8
#define NSEG 32               // H_/SEG
#define NBLK (B_ * NSEG)      // 512 blocks
#define RPAD 16
#define NSTAGE (SEG + 2 * RPAD)  // 40 staged rows

// min |dj| such that bit (j+dj) is set in the 256-bit row; 1<<28 if none.
__device__ __forceinline__ int nearest_dj(const unsigned long long* Brow, int j) {
    const int w = j >> 6, bpos = j & 63;
    int djr = 1 << 28;
    unsigned long long x = Brow[w] >> bpos;           // bit0 <-> column j
    if (x) djr = __builtin_ctzll(x);
    else {
        #pragma unroll
        for (int w2 = 1; w2 < 4; ++w2) {
            if (w2 > w && Brow[w2]) { djr = (w2 << 6) - j + __builtin_ctzll(Brow[w2]); break; }
        }
    }
    int djl = 1 << 28;
    unsigned long long y = Brow[w] << (63 - bpos);    // bit63 <-> column j
    if (y) djl = __builtin_clzll(y);
    else {
        #pragma unroll
        for (int w2 = 2; w2 >= 0; --w2) {
            if (w2 < w && Brow[w2]) { djl = j - ((w2 << 6) + 63 - __builtin_clzll(Brow[w2])); break; }
        }
    }
    return min(djl, djr);
}

// ---------------------------------------------------------------------------
// Mega-fused: ballot-pack mask rows (seg +/- RPAD) into LDS bits -> exact
// outward 2D ring search per pixel (integer d^2, early exit r^2 >= best) ->
// CE + weight -> one partial per block. No cross-block deps, no atomics.
//
// Exactness: any skipped row |di| = r' > r has d^2 >= r'^2 >= r^2 >= best;
// all distances are integers < 2^17 (exact in int and fp32). Rows outside the
// image stage as zero bits. A thread-local global-memory tail handles the
// (never-taken here) case of no bright pixel within RPAD rows.
// ---------------------------------------------------------------------------
__global__ void mega_fused_kernel(const float* __restrict__ pred,
                                  const int* __restrict__ mask,
                                  float* __restrict__ partials) {
    const int bs = blockIdx.x;
    const int b  = bs >> 5;
    const int s  = bs & (NSEG - 1);
    const int j  = threadIdx.x;
    const int i0 = s * SEG;

    __shared__ unsigned long long s_bits[NSTAGE][4];
    __shared__ float s_part[4];

    // prefetch logits early; latency hides under staging + search
    float pf0[SEG], pf1[SEG];
    const int pb = ((b * 2) << 16) + (i0 << 8) + j;
    #pragma unroll
    for (int rr = 0; rr < SEG; ++rr) {
        pf0[rr] = pred[pb + (rr << 8)];
        pf1[rr] = pred[pb + (rr << 8) + H_ * W_];
    }

    // ballot-pack mask rows i0-RPAD .. i0+SEG+RPAD-1 (out-of-image -> 0)
    const int mb = (b << 16) + j;
    #pragma unroll 4
    for (int t = 0; t < NSTAGE; ++t) {
        const int row = i0 - RPAD + t;               // uniform across block
        int mv = 0;
        if (row >= 0 && row < H_) mv = mask[mb + (row << 8)];
        unsigned long long bal = __ballot(mv != 0);
        if ((j & 63) == 0) s_bits[t][j >> 6] = bal;
    }
    __syncthreads();

    float vsum = 0.0f;
    #pragma unroll 1
    for (int rr = 0; rr < SEG; ++rr) {
        const int ribase = RPAD + rr;
        const int w = j >> 6, bpos = j & 63;
        const int tgt = (int)((s_bits[ribase][w] >> bpos) & 1ull);

        int best;
        if (tgt) {
            best = 0;
        } else {
            best = 1 << 28;
            int dj0 = nearest_dj(s_bits[ribase], j);
            if (dj0 <= 255) best = dj0 * dj0;
            int r = 1;
            for (; r <= RPAD && r * r < best; ++r) {
                int dja = nearest_dj(s_bits[ribase + r], j);
                if (dja <= 255) best = min(best, r * r + dja * dja);
                int djb = nearest_dj(s_bits[ribase - r], j);
                if (djb <= 255) best = min(best, r * r + djb * djb);
            }
            // exact slow tail (never taken for this input)
            const int i = i0 + rr;
            for (; r < H_ && r * r < best; ++r) {
                for (int sg = 0; sg < 2; ++sg) {
                    const int row = sg ? (i - r) : (i + r);
                    if (row < 0 || row >= H_) continue;
                    int lim = best - r * r;
                    for (int dj = 0; dj < W_ && dj * dj < lim; ++dj) {
                        int hit = 0;
                        if (j - dj >= 0) hit |= mask[(b << 16) + (row << 8) + (j - dj)];
                        if (j + dj < W_) hit |= mask[(b << 16) + (row << 8) + (j + dj)];
                        if (hit) { best = r * r + dj * dj; lim = best - r * r; break; }
                    }
                }
            }
        }

        float wgt = 0.0f;
        if (best < (1 << 28))
            wgt = __expf(-sqrtf((float)best) * INV_BETA);

        const float z  = tgt ? (pf1[rr] - pf0[rr]) : (pf0[rr] - pf1[rr]);
        const float ce = __logf(1.0f + __expf(-z));
        vsum += ce * (1.0f + ALPHA * wgt);
    }

    // block reduction -> one partial
    for (int off = 32; off > 0; off >>= 1)
        vsum += __shfl_down(vsum, off, 64);
    const int lane = j & 63;
    const int wid  = j >> 6;
    if (lane == 0) s_part[wid] = vsum;
    __syncthreads();
    if (j == 0)
        partials[bs] = s_part[0] + s_part[1] + s_part[2] + s_part[3];
}

// ---------------------------------------------------------------------------
// Final deterministic reduction of NBLK partials -> mean.
// ---------------------------------------------------------------------------
__global__ void final_reduce_kernel(const float* __restrict__ partials,
                                    float* __restrict__ out,
                                    float scale) {
    __shared__ float s_part[8];
    const int t = threadIdx.x;           // 512 threads
    float v = partials[t];
    for (int off = 32; off > 0; off >>= 1)
        v += __shfl_down(v, off, 64);
    if ((t & 63) == 0) s_part[t >> 6] = v;
    __syncthreads();
    if (t == 0) {
        float ssum = 0.0f;
        #pragma unroll
        for (int k = 0; k < 8; ++k) ssum += s_part[k];
        out[0] = ssum * scale;
    }
}

extern "C" void kernel_launch(void* const* d_in, const int* in_sizes, int n_in,
                              void* d_out, int out_size, void* d_ws, size_t ws_size,
                              hipStream_t stream) {
    const float* pred = (const float*)d_in[0];          // [B,2,H,W] f32
    const int*   mask = (const int*)d_in[1];            // [B,H,W] i32
    float* out = (float*)d_out;

    float* partials = (float*)d_ws;                     // NBLK floats

    mega_fused_kernel<<<NBLK, W_, 0, stream>>>(pred, mask, partials);
    final_reduce_kernel<<<1, NBLK, 0, stream>>>(partials, out,
                                                1.0f / (float)(B_ * H_ * W_));
}